// Round 9
// baseline (211.439 us; speedup 1.0000x reference)
//
#include <hip/hip_runtime.h>
#include <hip/hip_bf16.h>

typedef unsigned short ushort_t;
typedef unsigned int uint_t;
typedef __attribute__((ext_vector_type(8))) short short8;
typedef __attribute__((ext_vector_type(4))) float f32x4;
typedef __attribute__((ext_vector_type(4))) uint_t uint4_t;
typedef __attribute__((ext_vector_type(2))) uint_t uint2_t;

#define FOLD 128
// exp(COEFF*x^2) = 2^(-(x*S)^2);  S = sqrt(0.5/ln2)/DELTA, DELTA = 30/63
#define S_CONST 1.78357580f
#define DS_CONST 0.84932180f   /* DELTA * S_CONST = sqrt(0.5/ln2) */

__device__ __forceinline__ ushort_t f2bf(float f) {
    uint_t x = __builtin_bit_cast(uint_t, f);
    x += 0x7FFFu + ((x >> 16) & 1u);
    return (ushort_t)(x >> 16);
}

__device__ __forceinline__ uint_t pkbf(float a, float b) {
    // dword = bf16(b)<<16 | bf16(a), RNE (integer form; proven R3)
    uint_t xl = __builtin_bit_cast(uint_t, a);
    uint_t xh = __builtin_bit_cast(uint_t, b);
    uint_t rl = (xl + 0x7FFFu + ((xl >> 16) & 1u)) >> 16;
    uint_t rh = (xh + 0x7FFFu + ((xh >> 16) & 1u)) & 0xFFFF0000u;
    return rh | rl;
}

// LDS-only barrier: drains ds ops (lgkmcnt) but lets global loads/stores stay
// in flight across the barrier.
__device__ __forceinline__ void softbar() {
    asm volatile("s_waitcnt lgkmcnt(0)" ::: "memory");
    __builtin_amdgcn_s_barrier();
    asm volatile("" ::: "memory");
}

// Pack W1 (320x128) and W2 (128x128) fp32 row-major into bf16 MFMA fragment order.
// flat index i = ((ks*8 + nt)*64 + lane)*8 + j  <->  W[ks*32 + (lane>>4)*8 + j][nt*16 + (lane&15)]
__global__ __launch_bounds__(256) void pack_w(const float* __restrict__ W1,
                                              const float* __restrict__ W2,
                                              ushort_t* __restrict__ W1p,
                                              ushort_t* __restrict__ W2p) {
    int i = blockIdx.x * 256 + threadIdx.x;
    if (i < 40960) {
        int j = i & 7, l = (i >> 3) & 63, nt = (i >> 9) & 7, ks = i >> 12;
        int row = ks * 32 + ((l >> 4) << 3) + j;
        int col = nt * 16 + (l & 15);
        W1p[i] = f2bf(W1[row * FOLD + col]);
    } else if (i < 40960 + 16384) {
        int q = i - 40960;
        int j = q & 7, l = (q >> 3) & 63, nt = (q >> 9) & 7, ks = q >> 12;
        int row = ks * 32 + ((l >> 4) << 3) + j;
        int col = nt * 16 + (l & 15);
        W2p[q] = f2bf(W2[row * FOLD + col]);
    }
}

#define TEDGE 32

__global__ __launch_bounds__(256, 3) void fused(
    const float* __restrict__ lig,
    const float* __restrict__ p0, const float* __restrict__ p1,
    const float* __restrict__ p2, const float* __restrict__ p3,
    const float* __restrict__ p4,
    const ushort_t* __restrict__ W1p, const ushort_t* __restrict__ W2p,
    const float* __restrict__ b1, const float* __restrict__ b2,
    const int* __restrict__ src, const int* __restrict__ dst,
    float* __restrict__ out, int E)
{
    __shared__ float d_lds[2][5][TEDGE];
    __shared__ alignas(16) uint_t attrU[TEDGE * 160];  // [32 edges][320 k] bf16 dwords, XOR-swizzled
    __shared__ alignas(16) uint_t h_u[TEDGE * 64];     // h^T: [32 edges][128 ch] bf16 dwords, XOR-swizzled

    const int t = threadIdx.x;
    const int w = t >> 6;        // wave id: owns channels [w*32, w*32+32)
    const int l = t & 63;
    const int lrow = l & 15, lgrp = l >> 4;
    const int aswz = (lrow & 7) << 2;
    const int ntiles = (E + TEDGE - 1) / TEDGE;
    const int G = gridDim.x;

    // ---- Per-wave W1 fragments in registers (once per block); W2 refetched per tile ----
    const short8* W1v = reinterpret_cast<const short8*>(W1p);
    const short8* W2v = reinterpret_cast<const short8*>(W2p);
    short8 wb1[20];
    #pragma unroll
    for (int ks = 0; ks < 10; ++ks) {
        wb1[2 * ks]     = W1v[(ks * 8 + w * 2 + 0) * 64 + l];
        wb1[2 * ks + 1] = W1v[(ks * 8 + w * 2 + 1) * 64 + l];
    }
    f32x4 hb1[2], hb2[2];
    hb1[0] = *reinterpret_cast<const f32x4*>(&b1[w * 32 + lgrp * 4]);
    hb1[1] = *reinterpret_cast<const f32x4*>(&b1[w * 32 + 16 + lgrp * 4]);
    hb2[0] = *reinterpret_cast<const f32x4*>(&b2[w * 32 + lgrp * 4]);
    hb2[1] = *reinterpret_cast<const f32x4*>(&b2[w * 32 + 16 + lgrp * 4]);

    // gather mapping: 160 threads, unit = (channel c, edge m)
    const bool gth = (t < 160);
    const int g1c = t >> 5, g1m = t & 31;
    const float* GP = (g1c == 0) ? p0 : (g1c == 1) ? p1 : (g1c == 2) ? p2 : (g1c == 3) ? p3 : p4;

    // exp mapping: edge m2, k-chunk q2
    const int m2 = t >> 3, q2 = t & 7;
    const int swz = (m2 & 7) << 2;
    const float ubase = (float)(8 * q2) * DS_CONST;

    int tile = blockIdx.x;
    if (tile >= ntiles) return;

    // ---- Prologue: gather tile 0 (synchronous) ----
    if (gth) {
        int e = tile * TEDGE + g1m; if (e >= E) e = E - 1;
        int s = src[e], dd = dst[e];
        float dx = lig[3 * s]     - GP[3 * dd];
        float dy = lig[3 * s + 1] - GP[3 * dd + 1];
        float dz = lig[3 * s + 2] - GP[3 * dd + 2];
        d_lds[0][g1c][g1m] = sqrtf(dx * dx + dy * dy + dz * dz);
    }
    // ---- Prefetch src/dst indices for tile+G (depth-2 pipeline head) ----
    int sN = 0, dN = 0;
    if (gth && tile + G < ntiles) {
        int e = (tile + G) * TEDGE + g1m; if (e >= E) e = E - 1;
        sN = src[e]; dN = dst[e];
    }
    softbar();

    int buf = 0;
    while (true) {
        const int next = tile + G;
        const bool havenext = (next < ntiles);

        // ---- Issue next tile's position loads (indices already resident) ----
        float ax, ay, az, bx, by, bz;
        if (gth && havenext) {
            ax = lig[3 * sN];     bx = GP[3 * dN];
            ay = lig[3 * sN + 1]; by = GP[3 * dN + 1];
            az = lig[3 * sN + 2]; bz = GP[3 * dN + 2];
        }
        // ---- Issue src/dst for tile+2G ----
        int sN2 = sN, dN2 = dN;
        if (gth && next + G < ntiles) {
            int e = (next + G) * TEDGE + g1m; if (e >= E) e = E - 1;
            sN2 = src[e]; dN2 = dst[e];
        }

        // ---- Phase 2: RBF expansion -> attrU (1 edge x 40 k per thread) ----
        {
            float dv[5];
            #pragma unroll
            for (int c = 0; c < 5; ++c) dv[c] = d_lds[buf][c][m2];
            #pragma unroll
            for (int c = 0; c < 5; ++c) {
                float u0 = __builtin_fmaf(dv[c], S_CONST, -ubase);
                uint4_t vals;
                #pragma unroll
                for (int i = 0; i < 4; ++i) {
                    float ua = u0 - (float)(2 * i) * DS_CONST;
                    float ub = u0 - (float)(2 * i + 1) * DS_CONST;
                    float va = __builtin_amdgcn_exp2f(-(ua * ua));
                    float vb = __builtin_amdgcn_exp2f(-(ub * ub));
                    vals[i] = pkbf(va, vb);
                }
                int o = 32 * c + 4 * q2;
                *reinterpret_cast<uint4_t*>(&attrU[m2 * 160 + (o ^ swz)]) = vals;
            }
        }
        softbar();   // A — gather loads for next tile remain in flight

        // ---- Issue W2 fragment loads (L2-hit, consumed after barrier B) ----
        short8 wb2f[8];
        #pragma unroll
        for (int ks = 0; ks < 4; ++ks) {
            wb2f[2 * ks]     = W2v[(ks * 8 + w * 2 + 0) * 64 + l];
            wb2f[2 * ks + 1] = W2v[(ks * 8 + w * 2 + 1) * 64 + l];
        }

        // ---- Phase 3 (swapped): g1 = (attr@W1)^T; D: row=channel, col=edge ----
        f32x4 g1[2][2];
        #pragma unroll
        for (int nh = 0; nh < 2; ++nh)
            #pragma unroll
            for (int eh = 0; eh < 2; ++eh) g1[nh][eh] = f32x4{0.f, 0.f, 0.f, 0.f};
        __builtin_amdgcn_s_setprio(1);
        #pragma unroll
        for (int ks = 0; ks < 10; ++ks) {
            int o = ks * 16 + lgrp * 4;
            short8 af0 = *reinterpret_cast<const short8*>(&attrU[lrow * 160 + (o ^ aswz)]);
            short8 af1 = *reinterpret_cast<const short8*>(&attrU[(lrow + 16) * 160 + (o ^ aswz)]);
            g1[0][0] = __builtin_amdgcn_mfma_f32_16x16x32_bf16(wb1[2 * ks],     af0, g1[0][0], 0, 0, 0);
            g1[0][1] = __builtin_amdgcn_mfma_f32_16x16x32_bf16(wb1[2 * ks],     af1, g1[0][1], 0, 0, 0);
            g1[1][0] = __builtin_amdgcn_mfma_f32_16x16x32_bf16(wb1[2 * ks + 1], af0, g1[1][0], 0, 0, 0);
            g1[1][1] = __builtin_amdgcn_mfma_f32_16x16x32_bf16(wb1[2 * ks + 1], af1, g1[1][1], 0, 0, 0);
        }
        __builtin_amdgcn_s_setprio(0);

        // bias + relu + pack h^T: lane holds 4 consecutive channels of edge (eh*16+lrow)
        #pragma unroll
        for (int nh = 0; nh < 2; ++nh) {
            #pragma unroll
            for (int eh = 0; eh < 2; ++eh) {
                float v0 = fmaxf(g1[nh][eh][0] + hb1[nh][0], 0.f);
                float v1 = fmaxf(g1[nh][eh][1] + hb1[nh][1], 0.f);
                float v2 = fmaxf(g1[nh][eh][2] + hb1[nh][2], 0.f);
                float v3 = fmaxf(g1[nh][eh][3] + hb1[nh][3], 0.f);
                uint2_t pv;
                pv[0] = pkbf(v0, v1);
                pv[1] = pkbf(v2, v3);
                int e = eh * 16 + lrow;
                int dw = (w * 16 + nh * 8 + lgrp * 2) ^ ((e & 7) << 2);
                *reinterpret_cast<uint2_t*>(&h_u[e * 64 + dw]) = pv;
            }
        }

        // ---- Consume prefetched gathers LATE ----
        if (gth && havenext) {
            float dx = ax - bx, dy = ay - by, dz = az - bz;
            d_lds[buf ^ 1][g1c][g1m] = sqrtf(dx * dx + dy * dy + dz * dz);
        }
        sN = sN2; dN = dN2;
        softbar();   // B

        // ---- Phase 4 (swapped): o2 = (h@W2)^T ----
        f32x4 o2[2][2];
        #pragma unroll
        for (int nh = 0; nh < 2; ++nh)
            #pragma unroll
            for (int eh = 0; eh < 2; ++eh) o2[nh][eh] = f32x4{0.f, 0.f, 0.f, 0.f};
        __builtin_amdgcn_s_setprio(1);
        #pragma unroll
        for (int ks = 0; ks < 4; ++ks) {
            int dw = ks * 16 + lgrp * 4;
            short8 hf0 = *reinterpret_cast<const short8*>(&h_u[lrow * 64 + (dw ^ aswz)]);
            short8 hf1 = *reinterpret_cast<const short8*>(&h_u[(lrow + 16) * 64 + (dw ^ aswz)]);
            o2[0][0] = __builtin_amdgcn_mfma_f32_16x16x32_bf16(wb2f[2 * ks],     hf0, o2[0][0], 0, 0, 0);
            o2[0][1] = __builtin_amdgcn_mfma_f32_16x16x32_bf16(wb2f[2 * ks],     hf1, o2[0][1], 0, 0, 0);
            o2[1][0] = __builtin_amdgcn_mfma_f32_16x16x32_bf16(wb2f[2 * ks + 1], hf0, o2[1][0], 0, 0, 0);
            o2[1][1] = __builtin_amdgcn_mfma_f32_16x16x32_bf16(wb2f[2 * ks + 1], hf1, o2[1][1], 0, 0, 0);
        }
        __builtin_amdgcn_s_setprio(0);

        // ---- Phase 5: bias + non-temporal float4 stores ----
        const int e0i = tile * TEDGE;
        #pragma unroll
        for (int nh = 0; nh < 2; ++nh) {
            #pragma unroll
            for (int eh = 0; eh < 2; ++eh) {
                int e = e0i + eh * 16 + lrow;
                if (e < E) {
                    f32x4 v = o2[nh][eh] + hb2[nh];
                    __builtin_nontemporal_store(v,
                        reinterpret_cast<f32x4*>(&out[(size_t)e * FOLD + w * 32 + nh * 16 + lgrp * 4]));
                }
            }
        }

        if (!havenext) break;
        tile = next;
        buf ^= 1;
    }
}

extern "C" void kernel_launch(void* const* d_in, const int* in_sizes, int n_in,
                              void* d_out, int out_size, void* d_ws, size_t ws_size,
                              hipStream_t stream) {
    const float* lig = (const float*)d_in[0];
    const float* p0  = (const float*)d_in[1];
    const float* p1  = (const float*)d_in[2];
    const float* p2  = (const float*)d_in[3];
    const float* p3  = (const float*)d_in[4];
    const float* p4  = (const float*)d_in[5];
    const float* W1  = (const float*)d_in[6];
    const float* b1  = (const float*)d_in[7];
    const float* W2  = (const float*)d_in[8];
    const float* b2  = (const float*)d_in[9];
    const int* src   = (const int*)d_in[10];
    const int* dst   = (const int*)d_in[11];
    float* out = (float*)d_out;
    const int E = in_sizes[10];

    ushort_t* W1p = (ushort_t*)d_ws;
    ushort_t* W2p = W1p + 40960;

    pack_w<<<(40960 + 16384 + 255) / 256, 256, 0, stream>>>(W1, W2, W1p, W2p);

    int tiles = (E + TEDGE - 1) / TEDGE;
    int nblk = tiles < 1536 ? tiles : 1536;
    fused<<<nblk, 256, 0, stream>>>(lig, p0, p1, p2, p3, p4, W1p, W2p,
                                    b1, b2, src, dst, out, E);
}

// Round 10
// 111.881 us; speedup vs baseline: 1.8899x; 1.8899x over previous
//
#include <hip/hip_runtime.h>
#include <hip/hip_bf16.h>

typedef unsigned short ushort_t;
typedef unsigned int uint_t;
typedef __attribute__((ext_vector_type(8))) short short8;
typedef __attribute__((ext_vector_type(4))) float f32x4;
typedef __attribute__((ext_vector_type(4))) uint_t uint4_t;
typedef __attribute__((ext_vector_type(2))) uint_t uint2_t;

#define FOLD 128
// exp(COEFF*x^2) = 2^(-(x*S)^2);  S = sqrt(0.5/ln2)/DELTA, DELTA = 30/63
#define S_CONST 1.78357580f
#define DS_CONST 0.84932180f   /* DELTA * S_CONST = sqrt(0.5/ln2) */

__device__ __forceinline__ ushort_t f2bf(float f) {
    uint_t x = __builtin_bit_cast(uint_t, f);
    x += 0x7FFFu + ((x >> 16) & 1u);
    return (ushort_t)(x >> 16);
}

__device__ __forceinline__ uint_t pkbf(float a, float b) {
    // dword = bf16(b)<<16 | bf16(a), RNE via v_cvt_pk_bf16_f32 (1 inst).
    // memcpy (not bit_cast): __hip_bfloat162 is not trivially copyable (R5 lesson).
    __hip_bfloat162 h2 = __float22bfloat162_rn(float2{a, b});
    uint_t u;
    __builtin_memcpy(&u, &h2, sizeof(u));
    return u;
}

// LDS-only barrier: drains ds ops (lgkmcnt) but lets global loads/stores stay
// in flight across the barrier.
__device__ __forceinline__ void softbar() {
    asm volatile("s_waitcnt lgkmcnt(0)" ::: "memory");
    __builtin_amdgcn_s_barrier();
    asm volatile("" ::: "memory");
}

// Pack W1 (320x128) and W2 (128x128) fp32 row-major into bf16 MFMA fragment order.
// flat index i = ((ks*8 + nt)*64 + lane)*8 + j  <->  W[ks*32 + (lane>>4)*8 + j][nt*16 + (lane&15)]
__global__ __launch_bounds__(256) void pack_w(const float* __restrict__ W1,
                                              const float* __restrict__ W2,
                                              ushort_t* __restrict__ W1p,
                                              ushort_t* __restrict__ W2p) {
    int i = blockIdx.x * 256 + threadIdx.x;
    if (i < 40960) {
        int j = i & 7, l = (i >> 3) & 63, nt = (i >> 9) & 7, ks = i >> 12;
        int row = ks * 32 + ((l >> 4) << 3) + j;
        int col = nt * 16 + (l & 15);
        W1p[i] = f2bf(W1[row * FOLD + col]);
    } else if (i < 40960 + 16384) {
        int q = i - 40960;
        int j = q & 7, l = (q >> 3) & 63, nt = (q >> 9) & 7, ks = q >> 12;
        int row = ks * 32 + ((l >> 4) << 3) + j;
        int col = nt * 16 + (l & 15);
        W2p[q] = f2bf(W2[row * FOLD + col]);
    }
}

#define TEDGE 64

__global__ __launch_bounds__(256, 2) void fused(
    const float* __restrict__ lig,
    const float* __restrict__ p0, const float* __restrict__ p1,
    const float* __restrict__ p2, const float* __restrict__ p3,
    const float* __restrict__ p4,
    const ushort_t* __restrict__ W1p, const ushort_t* __restrict__ W2p,
    const float* __restrict__ b1, const float* __restrict__ b2,
    const int* __restrict__ src, const int* __restrict__ dst,
    float* __restrict__ out, int E)
{
    __shared__ float d_lds[2][5][TEDGE];
    __shared__ alignas(16) uint_t attrU[TEDGE * 160];  // [64 edges][320 k] bf16 dwords, XOR-swizzled
    __shared__ alignas(16) uint_t h_u[TEDGE * 64];     // h^T: [64 edges][128 ch] bf16 dwords, XOR-swizzled

    const int t = threadIdx.x;
    const int w = t >> 6;        // wave id: owns channels [w*32, w*32+32)
    const int l = t & 63;
    const int lrow = l & 15, lgrp = l >> 4;
    const int aswz = (lrow & 7) << 2;
    const int ntiles = (E + TEDGE - 1) / TEDGE;
    const int G = gridDim.x;

    // ---- Per-wave W fragments in registers (once per block) ----
    const short8* W1v = reinterpret_cast<const short8*>(W1p);
    const short8* W2v = reinterpret_cast<const short8*>(W2p);
    short8 wb1[20], wb2[8];
    #pragma unroll
    for (int ks = 0; ks < 10; ++ks) {
        wb1[2 * ks]     = W1v[(ks * 8 + w * 2 + 0) * 64 + l];
        wb1[2 * ks + 1] = W1v[(ks * 8 + w * 2 + 1) * 64 + l];
    }
    #pragma unroll
    for (int ks = 0; ks < 4; ++ks) {
        wb2[2 * ks]     = W2v[(ks * 8 + w * 2 + 0) * 64 + l];
        wb2[2 * ks + 1] = W2v[(ks * 8 + w * 2 + 1) * 64 + l];
    }
    f32x4 hb1[2], hb2[2];
    hb1[0] = *reinterpret_cast<const f32x4*>(&b1[w * 32 + lgrp * 4]);
    hb1[1] = *reinterpret_cast<const f32x4*>(&b1[w * 32 + 16 + lgrp * 4]);
    hb2[0] = *reinterpret_cast<const f32x4*>(&b2[w * 32 + lgrp * 4]);
    hb2[1] = *reinterpret_cast<const f32x4*>(&b2[w * 32 + 16 + lgrp * 4]);

    // gather mapping: unit g = c*64+m; thread t does g=t, threads t<64 also channel 4.
    const int g1c = t >> 6, g1m = t & 63;
    const bool gth2 = (t < 64);
    const float* GP1 = (g1c == 0) ? p0 : (g1c == 1) ? p1 : (g1c == 2) ? p2 : p3;
    const float* GP2 = p4;

    // exp mapping: edges m2 and m2+32, k-chunk q2
    const int m2 = t >> 3, q2 = t & 7;
    const float ubase = (float)(8 * q2) * DS_CONST;

    int tile = blockIdx.x;
    if (tile >= ntiles) return;

    // ---- Prologue: gather tile 0 (synchronous) ----
    {
        int e = tile * TEDGE + g1m; if (e >= E) e = E - 1;
        int s = src[e], dd = dst[e];
        float dx = lig[3 * s]     - GP1[3 * dd];
        float dy = lig[3 * s + 1] - GP1[3 * dd + 1];
        float dz = lig[3 * s + 2] - GP1[3 * dd + 2];
        d_lds[0][g1c][g1m] = sqrtf(dx * dx + dy * dy + dz * dz);
        if (gth2) {
            float ex = lig[3 * s]     - GP2[3 * dd];
            float ey = lig[3 * s + 1] - GP2[3 * dd + 1];
            float ez = lig[3 * s + 2] - GP2[3 * dd + 2];
            d_lds[0][4][g1m] = sqrtf(ex * ex + ey * ey + ez * ez);
        }
    }
    // ---- Prefetch src/dst indices for tile+G (depth-2 pipeline head) ----
    int sN = 0, dN = 0;
    if (tile + G < ntiles) {
        int e = (tile + G) * TEDGE + g1m; if (e >= E) e = E - 1;
        sN = src[e]; dN = dst[e];
    }
    softbar();

    int buf = 0;
    while (true) {
        const int next = tile + G;
        const bool havenext = (next < ntiles);

        // ---- Issue next tile's position loads (indices already resident) ----
        float ax, ay, az, bx, by, bz, cx, cy, cz;
        if (havenext) {
            ax = lig[3 * sN];     bx = GP1[3 * dN];
            ay = lig[3 * sN + 1]; by = GP1[3 * dN + 1];
            az = lig[3 * sN + 2]; bz = GP1[3 * dN + 2];
            if (gth2) { cx = GP2[3 * dN]; cy = GP2[3 * dN + 1]; cz = GP2[3 * dN + 2]; }
        }
        // ---- Issue src/dst for tile+2G ----
        int sN2 = sN, dN2 = dN;
        if (next + G < ntiles) {
            int e = (next + G) * TEDGE + g1m; if (e >= E) e = E - 1;
            sN2 = src[e]; dN2 = dst[e];
        }

        // ---- Phase 2: RBF expansion -> attrU (2 edges per thread) ----
        #pragma unroll
        for (int half = 0; half < 2; ++half) {
            const int m = m2 + half * 32;
            const int swz = (m & 7) << 2;
            float dv[5];
            #pragma unroll
            for (int c = 0; c < 5; ++c) dv[c] = d_lds[buf][c][m];
            #pragma unroll
            for (int c = 0; c < 5; ++c) {
                float u0 = __builtin_fmaf(dv[c], S_CONST, -ubase);
                uint4_t vals;
                #pragma unroll
                for (int i = 0; i < 4; ++i) {
                    float ua = u0 - (float)(2 * i) * DS_CONST;
                    float ub = u0 - (float)(2 * i + 1) * DS_CONST;
                    float va = __builtin_amdgcn_exp2f(-(ua * ua));
                    float vb = __builtin_amdgcn_exp2f(-(ub * ub));
                    vals[i] = pkbf(va, vb);
                }
                int o = 32 * c + 4 * q2;
                *reinterpret_cast<uint4_t*>(&attrU[m * 160 + (o ^ swz)]) = vals;
            }
        }
        softbar();   // A — gather loads for next tile remain in flight

        // ---- Phase 3 (swapped): g1 = (attr@W1)^T; D: row=channel, col=edge ----
        f32x4 g1[2][4];
        #pragma unroll
        for (int nh = 0; nh < 2; ++nh)
            #pragma unroll
            for (int eh = 0; eh < 4; ++eh) g1[nh][eh] = f32x4{0.f, 0.f, 0.f, 0.f};
        #pragma unroll
        for (int ks = 0; ks < 10; ++ks) {
            int o = ks * 16 + lgrp * 4;
            short8 af[4];
            #pragma unroll
            for (int eh = 0; eh < 4; ++eh)
                af[eh] = *reinterpret_cast<const short8*>(&attrU[(lrow + eh * 16) * 160 + (o ^ aswz)]);
            #pragma unroll
            for (int eh = 0; eh < 4; ++eh) {
                g1[0][eh] = __builtin_amdgcn_mfma_f32_16x16x32_bf16(wb1[2 * ks],     af[eh], g1[0][eh], 0, 0, 0);
                g1[1][eh] = __builtin_amdgcn_mfma_f32_16x16x32_bf16(wb1[2 * ks + 1], af[eh], g1[1][eh], 0, 0, 0);
            }
        }

        // bias + relu + pack h^T: lane holds 4 consecutive channels of edge (eh*16+lrow)
        #pragma unroll
        for (int nh = 0; nh < 2; ++nh) {
            #pragma unroll
            for (int eh = 0; eh < 4; ++eh) {
                float v0 = fmaxf(g1[nh][eh][0] + hb1[nh][0], 0.f);
                float v1 = fmaxf(g1[nh][eh][1] + hb1[nh][1], 0.f);
                float v2 = fmaxf(g1[nh][eh][2] + hb1[nh][2], 0.f);
                float v3 = fmaxf(g1[nh][eh][3] + hb1[nh][3], 0.f);
                uint2_t pv;
                pv[0] = pkbf(v0, v1);
                pv[1] = pkbf(v2, v3);
                int e = eh * 16 + lrow;
                int dw = (w * 16 + nh * 8 + lgrp * 2) ^ ((e & 7) << 2);
                *reinterpret_cast<uint2_t*>(&h_u[e * 64 + dw]) = pv;
            }
        }

        // ---- Consume prefetched gathers LATE (~exp+GEMM1 cycles in flight) ----
        if (havenext) {
            float dx = ax - bx, dy = ay - by, dz = az - bz;
            d_lds[buf ^ 1][g1c][g1m] = sqrtf(dx * dx + dy * dy + dz * dz);
            if (gth2) {
                float ex = ax - cx, ey = ay - cy, ez = az - cz;
                d_lds[buf ^ 1][4][g1m] = sqrtf(ex * ex + ey * ey + ez * ez);
            }
        }
        sN = sN2; dN = dN2;
        softbar();   // B

        // ---- Phase 4 (swapped): o2 = (h@W2)^T ----
        f32x4 o2[2][4];
        #pragma unroll
        for (int nh = 0; nh < 2; ++nh)
            #pragma unroll
            for (int eh = 0; eh < 4; ++eh) o2[nh][eh] = f32x4{0.f, 0.f, 0.f, 0.f};
        #pragma unroll
        for (int ks = 0; ks < 4; ++ks) {
            int dw = ks * 16 + lgrp * 4;
            short8 hf[4];
            #pragma unroll
            for (int eh = 0; eh < 4; ++eh)
                hf[eh] = *reinterpret_cast<const short8*>(&h_u[(lrow + eh * 16) * 64 + (dw ^ aswz)]);
            #pragma unroll
            for (int eh = 0; eh < 4; ++eh) {
                o2[0][eh] = __builtin_amdgcn_mfma_f32_16x16x32_bf16(wb2[2 * ks],     hf[eh], o2[0][eh], 0, 0, 0);
                o2[1][eh] = __builtin_amdgcn_mfma_f32_16x16x32_bf16(wb2[2 * ks + 1], hf[eh], o2[1][eh], 0, 0, 0);
            }
        }

        // ---- Phase 5: bias + non-temporal float4 stores (out is never re-read) ----
        const int e0i = tile * TEDGE;
        #pragma unroll
        for (int nh = 0; nh < 2; ++nh) {
            #pragma unroll
            for (int eh = 0; eh < 4; ++eh) {
                int e = e0i + eh * 16 + lrow;
                if (e < E) {
                    f32x4 v = o2[nh][eh] + hb2[nh];
                    __builtin_nontemporal_store(v,
                        reinterpret_cast<f32x4*>(&out[(size_t)e * FOLD + w * 32 + nh * 16 + lgrp * 4]));
                }
            }
        }

        if (!havenext) break;
        tile = next;
        buf ^= 1;
    }
}

extern "C" void kernel_launch(void* const* d_in, const int* in_sizes, int n_in,
                              void* d_out, int out_size, void* d_ws, size_t ws_size,
                              hipStream_t stream) {
    const float* lig = (const float*)d_in[0];
    const float* p0  = (const float*)d_in[1];
    const float* p1  = (const float*)d_in[2];
    const float* p2  = (const float*)d_in[3];
    const float* p3  = (const float*)d_in[4];
    const float* p4  = (const float*)d_in[5];
    const float* W1  = (const float*)d_in[6];
    const float* b1  = (const float*)d_in[7];
    const float* W2  = (const float*)d_in[8];
    const float* b2  = (const float*)d_in[9];
    const int* src   = (const int*)d_in[10];
    const int* dst   = (const int*)d_in[11];
    float* out = (float*)d_out;
    const int E = in_sizes[10];

    ushort_t* W1p = (ushort_t*)d_ws;
    ushort_t* W2p = W1p + 40960;

    pack_w<<<(40960 + 16384 + 255) / 256, 256, 0, stream>>>(W1, W2, W1p, W2p);

    int tiles = (E + TEDGE - 1) / TEDGE;
    int nblk = tiles < 1024 ? tiles : 1024;
    fused<<<nblk, 256, 0, stream>>>(lig, p0, p1, p2, p3, p4, W1p, W2p,
                                    b1, b2, src, dst, out, E);
}

// Round 11
// 110.337 us; speedup vs baseline: 1.9163x; 1.0140x over previous
//
#include <hip/hip_runtime.h>
#include <hip/hip_bf16.h>

typedef unsigned short ushort_t;
typedef unsigned int uint_t;
typedef __attribute__((ext_vector_type(8))) short short8;
typedef __attribute__((ext_vector_type(4))) float f32x4;
typedef __attribute__((ext_vector_type(2))) uint_t uint2_t;

#define FOLD 128
// exp(COEFF*x^2) = 2^(-(x*S)^2);  S = sqrt(0.5/ln2)/DELTA, DELTA = 30/63
#define S_CONST 1.78357580f
#define DS_CONST 0.84932180f   /* DELTA * S_CONST = sqrt(0.5/ln2) */

__device__ __forceinline__ ushort_t f2bf(float f) {
    uint_t x = __builtin_bit_cast(uint_t, f);
    x += 0x7FFFu + ((x >> 16) & 1u);
    return (ushort_t)(x >> 16);
}

__device__ __forceinline__ uint_t pkbf(float a, float b) {
    // dword = bf16(b)<<16 | bf16(a), RNE via v_cvt_pk_bf16_f32 (1 inst).
    __hip_bfloat162 h2 = __float22bfloat162_rn(float2{a, b});
    uint_t u;
    __builtin_memcpy(&u, &h2, sizeof(u));
    return u;
}

// LDS-only barrier: drains ds ops (lgkmcnt) but lets global loads/stores stay
// in flight across the barrier.
__device__ __forceinline__ void softbar() {
    asm volatile("s_waitcnt lgkmcnt(0)" ::: "memory");
    __builtin_amdgcn_s_barrier();
    asm volatile("" ::: "memory");
}

// Pack W1 (320x128) and W2 (128x128) fp32 row-major into bf16 MFMA fragment order.
// flat index i = ((ks*8 + nt)*64 + lane)*8 + j  <->  W[ks*32 + (lane>>4)*8 + j][nt*16 + (lane&15)]
__global__ __launch_bounds__(256) void pack_w(const float* __restrict__ W1,
                                              const float* __restrict__ W2,
                                              ushort_t* __restrict__ W1p,
                                              ushort_t* __restrict__ W2p) {
    int i = blockIdx.x * 256 + threadIdx.x;
    if (i < 40960) {
        int j = i & 7, l = (i >> 3) & 63, nt = (i >> 9) & 7, ks = i >> 12;
        int row = ks * 32 + ((l >> 4) << 3) + j;
        int col = nt * 16 + (l & 15);
        W1p[i] = f2bf(W1[row * FOLD + col]);
    } else if (i < 40960 + 16384) {
        int q = i - 40960;
        int j = q & 7, l = (q >> 3) & 63, nt = (q >> 9) & 7, ks = q >> 12;
        int row = ks * 32 + ((l >> 4) << 3) + j;
        int col = nt * 16 + (l & 15);
        W2p[q] = f2bf(W2[row * FOLD + col]);
    }
}

#define TEDGE 32

// 512 threads = 8 waves; wave w owns output channels [w*16, w*16+16).
// wb1 = 10 frags (40 VGPR), wb2 = 4 frags (16 VGPR) -> fits 128-reg cap ->
// 4 waves/SIMD (16 waves/CU), double the R10 occupancy.
__global__ __launch_bounds__(512, 4) void fused(
    const float* __restrict__ lig,
    const float* __restrict__ p0, const float* __restrict__ p1,
    const float* __restrict__ p2, const float* __restrict__ p3,
    const float* __restrict__ p4,
    const ushort_t* __restrict__ W1p, const ushort_t* __restrict__ W2p,
    const float* __restrict__ b1, const float* __restrict__ b2,
    const int* __restrict__ src, const int* __restrict__ dst,
    float* __restrict__ out, int E)
{
    __shared__ float d_lds[2][5][TEDGE];
    __shared__ alignas(16) uint_t attrU[TEDGE * 160];  // [32 edges][320 k] bf16 dwords, XOR-swizzled
    __shared__ alignas(16) uint_t h_u[TEDGE * 64];     // h^T: [32 edges][128 ch] bf16 dwords, XOR-swizzled

    const int t = threadIdx.x;
    const int w = t >> 6;        // wave 0..7: channels [w*16, w*16+16)
    const int l = t & 63;
    const int lrow = l & 15, lgrp = l >> 4;
    const int aswz = (lrow & 7) << 2;
    const int ntiles = (E + TEDGE - 1) / TEDGE;
    const int G = gridDim.x;

    // ---- Per-wave W fragments in registers (once per block) ----
    const short8* W1v = reinterpret_cast<const short8*>(W1p);
    const short8* W2v = reinterpret_cast<const short8*>(W2p);
    short8 wb1[10], wb2[4];
    #pragma unroll
    for (int ks = 0; ks < 10; ++ks) wb1[ks] = W1v[(ks * 8 + w) * 64 + l];
    #pragma unroll
    for (int ks = 0; ks < 4; ++ks)  wb2[ks] = W2v[(ks * 8 + w) * 64 + l];
    f32x4 hb1 = *reinterpret_cast<const f32x4*>(&b1[w * 16 + lgrp * 4]);
    f32x4 hb2 = *reinterpret_cast<const f32x4*>(&b2[w * 16 + lgrp * 4]);

    // gather mapping: 160 threads, unit = (channel g1c, edge g1m)
    const bool gth = (t < 160);
    const int g1c = t >> 5, g1m = t & 31;
    const float* GP = (g1c == 0) ? p0 : (g1c == 1) ? p1 : (g1c == 2) ? p2 : (g1c == 3) ? p3 : p4;

    // exp mapping: edge m2 = t>>4 (0..31), k-quad q2 = t&15 (4 elems per channel)
    const int m2 = t >> 4, q2 = t & 15;
    const int swz = (m2 & 7) << 2;
    const float ubase = (float)(4 * q2) * DS_CONST;

    int tile = blockIdx.x;
    if (tile >= ntiles) return;

    // ---- Prologue: gather tile 0 (synchronous) ----
    if (gth) {
        int e = tile * TEDGE + g1m; if (e >= E) e = E - 1;
        int s = src[e], dd = dst[e];
        float dx = lig[3 * s]     - GP[3 * dd];
        float dy = lig[3 * s + 1] - GP[3 * dd + 1];
        float dz = lig[3 * s + 2] - GP[3 * dd + 2];
        d_lds[0][g1c][g1m] = sqrtf(dx * dx + dy * dy + dz * dz);
    }
    // ---- Prefetch src/dst indices for tile+G (depth-2 pipeline head) ----
    int sN = 0, dN = 0;
    if (gth && tile + G < ntiles) {
        int e = (tile + G) * TEDGE + g1m; if (e >= E) e = E - 1;
        sN = src[e]; dN = dst[e];
    }
    softbar();

    int buf = 0;
    while (true) {
        const int next = tile + G;
        const bool havenext = (next < ntiles);

        // ---- Issue next tile's position loads (indices already resident) ----
        float ax, ay, az, bx, by, bz;
        if (gth && havenext) {
            ax = lig[3 * sN];     bx = GP[3 * dN];
            ay = lig[3 * sN + 1]; by = GP[3 * dN + 1];
            az = lig[3 * sN + 2]; bz = GP[3 * dN + 2];
        }
        // ---- Issue src/dst for tile+2G ----
        int sN2 = sN, dN2 = dN;
        if (gth && next + G < ntiles) {
            int e = (next + G) * TEDGE + g1m; if (e >= E) e = E - 1;
            sN2 = src[e]; dN2 = dst[e];
        }

        // ---- Phase 2: RBF expansion -> attrU (1 edge x 4 k per channel per thread) ----
        {
            float dv[5];
            #pragma unroll
            for (int c = 0; c < 5; ++c) dv[c] = d_lds[buf][c][m2];
            #pragma unroll
            for (int c = 0; c < 5; ++c) {
                float u0 = __builtin_fmaf(dv[c], S_CONST, -ubase);
                float u1 = u0 - DS_CONST;
                float u2 = u0 - 2.0f * DS_CONST;
                float u3 = u0 - 3.0f * DS_CONST;
                float v0 = __builtin_amdgcn_exp2f(-(u0 * u0));
                float v1 = __builtin_amdgcn_exp2f(-(u1 * u1));
                float v2 = __builtin_amdgcn_exp2f(-(u2 * u2));
                float v3 = __builtin_amdgcn_exp2f(-(u3 * u3));
                uint2_t pv;
                pv[0] = pkbf(v0, v1);
                pv[1] = pkbf(v2, v3);
                int o = 32 * c + 2 * q2;
                *reinterpret_cast<uint2_t*>(&attrU[m2 * 160 + (o ^ swz)]) = pv;
            }
        }
        softbar();   // A — gather loads for next tile remain in flight

        // ---- Phase 3 (swapped): g1 = (attr@W1)^T slice; D: row=channel, col=edge ----
        f32x4 g1[2] = {{0.f,0.f,0.f,0.f},{0.f,0.f,0.f,0.f}};   // [ehalf]
        #pragma unroll
        for (int ks = 0; ks < 10; ++ks) {
            int o = ks * 16 + lgrp * 4;
            short8 af0 = *reinterpret_cast<const short8*>(&attrU[lrow * 160 + (o ^ aswz)]);
            short8 af1 = *reinterpret_cast<const short8*>(&attrU[(lrow + 16) * 160 + (o ^ aswz)]);
            g1[0] = __builtin_amdgcn_mfma_f32_16x16x32_bf16(wb1[ks], af0, g1[0], 0, 0, 0);
            g1[1] = __builtin_amdgcn_mfma_f32_16x16x32_bf16(wb1[ks], af1, g1[1], 0, 0, 0);
        }

        // bias + relu + pack h^T: lane holds 4 consecutive channels of edge (eh*16+lrow)
        #pragma unroll
        for (int eh = 0; eh < 2; ++eh) {
            float v0 = fmaxf(g1[eh][0] + hb1[0], 0.f);
            float v1 = fmaxf(g1[eh][1] + hb1[1], 0.f);
            float v2 = fmaxf(g1[eh][2] + hb1[2], 0.f);
            float v3 = fmaxf(g1[eh][3] + hb1[3], 0.f);
            uint2_t pv;
            pv[0] = pkbf(v0, v1);
            pv[1] = pkbf(v2, v3);
            int e = eh * 16 + lrow;
            int dw = (w * 8 + lgrp * 2) ^ ((e & 7) << 2);
            *reinterpret_cast<uint2_t*>(&h_u[e * 64 + dw]) = pv;
        }

        // ---- Consume prefetched gathers LATE ----
        if (gth && havenext) {
            float dx = ax - bx, dy = ay - by, dz = az - bz;
            d_lds[buf ^ 1][g1c][g1m] = sqrtf(dx * dx + dy * dy + dz * dz);
        }
        sN = sN2; dN = dN2;
        softbar();   // B

        // ---- Phase 4 (swapped): o2 = (h@W2)^T slice ----
        f32x4 o2[2] = {{0.f,0.f,0.f,0.f},{0.f,0.f,0.f,0.f}};
        #pragma unroll
        for (int ks = 0; ks < 4; ++ks) {
            int dw = ks * 16 + lgrp * 4;
            short8 hf0 = *reinterpret_cast<const short8*>(&h_u[lrow * 64 + (dw ^ aswz)]);
            short8 hf1 = *reinterpret_cast<const short8*>(&h_u[(lrow + 16) * 64 + (dw ^ aswz)]);
            o2[0] = __builtin_amdgcn_mfma_f32_16x16x32_bf16(wb2[ks], hf0, o2[0], 0, 0, 0);
            o2[1] = __builtin_amdgcn_mfma_f32_16x16x32_bf16(wb2[ks], hf1, o2[1], 0, 0, 0);
        }

        // ---- Phase 5: bias + non-temporal float4 stores ----
        const int e0i = tile * TEDGE;
        #pragma unroll
        for (int eh = 0; eh < 2; ++eh) {
            int e = e0i + eh * 16 + lrow;
            if (e < E) {
                f32x4 v = o2[eh] + hb2;
                __builtin_nontemporal_store(v,
                    reinterpret_cast<f32x4*>(&out[(size_t)e * FOLD + w * 16 + lgrp * 4]));
            }
        }

        if (!havenext) break;
        tile = next;
        buf ^= 1;
    }
}

extern "C" void kernel_launch(void* const* d_in, const int* in_sizes, int n_in,
                              void* d_out, int out_size, void* d_ws, size_t ws_size,
                              hipStream_t stream) {
    const float* lig = (const float*)d_in[0];
    const float* p0  = (const float*)d_in[1];
    const float* p1  = (const float*)d_in[2];
    const float* p2  = (const float*)d_in[3];
    const float* p3  = (const float*)d_in[4];
    const float* p4  = (const float*)d_in[5];
    const float* W1  = (const float*)d_in[6];
    const float* b1  = (const float*)d_in[7];
    const float* W2  = (const float*)d_in[8];
    const float* b2  = (const float*)d_in[9];
    const int* src   = (const int*)d_in[10];
    const int* dst   = (const int*)d_in[11];
    float* out = (float*)d_out;
    const int E = in_sizes[10];

    ushort_t* W1p = (ushort_t*)d_ws;
    ushort_t* W2p = W1p + 40960;

    pack_w<<<(40960 + 16384 + 255) / 256, 256, 0, stream>>>(W1, W2, W1p, W2p);

    int tiles = (E + TEDGE - 1) / TEDGE;
    int nblk = tiles < 512 ? tiles : 512;
    fused<<<nblk, 512, 0, stream>>>(lig, p0, p1, p2, p3, p4, W1p, W2p,
                                    b1, b2, src, dst, out, E);
}